// Round 8
// baseline (272.514 us; speedup 1.0000x reference)
//
#include <hip/hip_runtime.h>

#define NN 50000
#define NREL 3
#define NE 500000
#define DIN 128
#define DHID 256
#define DOUT 128

#define NBUK 98          // ceil(50000/512) dst-buckets of 512 nodes
#define CAP 8192         // padded-slot capacity per bucket (E~6900, sd~100)
#define EPB 4096         // edges per pass-A block
#define NCHK ((NE + EPB - 1) / EPB)   // 123
#define PA_BLKS (NREL * NCHK)         // 369
#define F2B_BLKS 6250                 // NN*DIN/4/256
#define ZROW ((uint)NN << 8)          // scaled dummy -> zero row (byte offset)
#define MM1S_BLKS 782                 // 391 m-tiles x 2 n-tiles (self GEMM, fused with G1)

typedef unsigned int uint;
typedef unsigned short ushort;
typedef __attribute__((ext_vector_type(8))) short bf16x8;
typedef __attribute__((ext_vector_type(4))) float f32x4;
typedef __attribute__((ext_vector_type(2))) float f32x2;

using gptr_t = const __attribute__((address_space(1))) unsigned int*;
using lptr_t = __attribute__((address_space(3))) unsigned int*;

__device__ __forceinline__ ushort f2bf(float f) {
    uint u = __float_as_uint(f);
    uint r = (u + 0x7fffu + ((u >> 16) & 1u)) >> 16;
    return (ushort)r;
}
__device__ __forceinline__ void acc2(f32x2& a, uint u) {
    f32x2 t;
    t.x = __uint_as_float(u << 16);
    t.y = __uint_as_float(u & 0xffff0000u);
    a += t;   // v_pk_add_f32
}
__device__ __forceinline__ void acc16(f32x2* a, uint4 v) {
    acc2(a[0], v.x); acc2(a[1], v.y); acc2(a[2], v.z); acc2(a[3], v.w);
}

// ---------------- pass A (bucket edges) + prep (fused grid) ----------------
__global__ __launch_bounds__(256) void pass_a_prep(
    const int* __restrict__ src, const int* __restrict__ dst,
    int* __restrict__ bcursor, uint* __restrict__ pairs,
    const float* __restrict__ x, ushort* __restrict__ xb,
    const float* __restrict__ ws1, const float* __restrict__ wn1, ushort* __restrict__ Bt1,
    const float* __restrict__ ws2, const float* __restrict__ wn2, ushort* __restrict__ Bt2,
    const float* __restrict__ b1, float* __restrict__ bsum1,
    const float* __restrict__ b2, float* __restrict__ bsum2,
    ushort* __restrict__ agg0, ushort* __restrict__ agg1, ushort* __restrict__ agg2) {
    int blk = blockIdx.x, tid = threadIdx.x;
    if (blk < PA_BLKS) {
        int r = blk / NCHK;
        int chunk = blk % NCHK;
        int e0 = chunk * EPB;
        int nedge = min(EPB, NE - e0);
        const int* S = src + (size_t)r * NE + e0;
        const int* D = dst + (size_t)r * NE + e0;
        __shared__ int cnt[NBUK], base[NBUK], cur[NBUK];
        if (tid < NBUK) { cnt[tid] = 0; cur[tid] = 0; }
        __syncthreads();
        uint pk[16];
        int bk[16];
        bool val[16];
#pragma unroll
        for (int j = 0; j < 16; ++j) {
            int e = j * 256 + tid;
            val[j] = e < nedge;
            int d = val[j] ? D[e] : 0;
            int s = val[j] ? S[e] : 0;
            bk[j] = d >> 9;
            pk[j] = ((uint)s << 9) | (uint)(d & 511);
            if (val[j]) atomicAdd(&cnt[bk[j]], 1);
        }
        __syncthreads();
        if (tid < NBUK) base[tid] = atomicAdd(&bcursor[r * NBUK + tid], cnt[tid]);
        __syncthreads();
#pragma unroll
        for (int j = 0; j < 16; ++j) {
            if (val[j]) {
                int slot = base[bk[j]] + atomicAdd(&cur[bk[j]], 1);
                if (slot < CAP) pairs[(size_t)(r * NBUK + bk[j]) * CAP + slot] = pk[j];
            }
        }
        return;
    }
    blk -= PA_BLKS;
    if (blk < F2B_BLKS) {
        int t = blk * 256 + tid;   // < NN*DIN/4, exact
        float4 v = *(const float4*)(x + (size_t)t * 4);
        uint2 p;
        p.x = (uint)f2bf(v.x) | ((uint)f2bf(v.y) << 16);
        p.y = (uint)f2bf(v.z) | ((uint)f2bf(v.w) << 16);
        *(uint2*)(xb + (size_t)t * 4) = p;
    } else if (blk < F2B_BLKS + 512) {
        int t = (blk - F2B_BLKS) * 256 + tid;  // < 256*512
        int n = t >> 9, k = t & 511;
        int b = k >> 7, kk = k & 127;
        float v;
        if (b == 0)
            v = ws1[kk * 256 + n] + ws1[128 * 256 + kk * 256 + n] + ws1[2 * 128 * 256 + kk * 256 + n];
        else
            v = wn1[(size_t)(b - 1) * 128 * 256 + kk * 256 + n];
        Bt1[t] = f2bf(v);
    } else if (blk < F2B_BLKS + 1024) {
        int t = (blk - F2B_BLKS - 512) * 256 + tid;  // < 512*256
        int n = t >> 8, k = t & 255;
        int c = n >> 7, j = n & 127;
        float v;
        if (c == 0)
            v = ws2[k * 128 + j] + ws2[256 * 128 + k * 128 + j] + ws2[2 * 256 * 128 + k * 128 + j];
        else
            v = wn2[(size_t)(c - 1) * 256 * 128 + k * 128 + j];
        Bt2[t] = f2bf(v);
    } else {
        // bias sums + zero rows (row NN of xb/agg0/agg1/agg2)
        if (tid < DHID) bsum1[tid] = b1[tid] + b1[DHID + tid] + b1[2 * DHID + tid];
        if (tid < DOUT) bsum2[tid] = b2[tid] + b2[DOUT + tid] + b2[2 * DOUT + tid];
        if (tid >= 192 && tid < 256) {
            int b = (tid - 192) >> 4, i = tid & 15;
            ushort* row = (b == 0) ? xb : (b == 1) ? agg0 : (b == 2) ? agg1 : agg2;
            uint4 z = {0u, 0u, 0u, 0u};
            *(uint4*)(row + (size_t)NN * 128 + i * 8) = z;
        }
    }
}

// ---------------- pass B: per-bucket CSR with 8-padded node slots ----------------
__global__ __launch_bounds__(256) void pass_b(const uint* __restrict__ pairs,
                                              const int* __restrict__ bcnt,
                                              uint* __restrict__ srclist,
                                              int2* __restrict__ nd) {
    int blk = blockIdx.x;
    int b = blk % NBUK;
    int r = blk / NBUK;
    int node_base = b * 512;
    int count = min(bcnt[blk], CAP);
    int obase = blk * CAP;
    const uint* pp = pairs + (size_t)blk * CAP;
    __shared__ int hist[512];
    __shared__ int cur[512];
    __shared__ int sc[256];
    int tid = threadIdx.x;
    hist[tid] = 0;
    hist[tid + 256] = 0;
    __syncthreads();
    for (int i = tid; i < count; i += 256) atomicAdd(&hist[pp[i] & 511], 1);
    __syncthreads();
    int v0 = hist[2 * tid], v1 = hist[2 * tid + 1];
    int p0 = (v0 + 7) & ~7;                 // padded slot sizes
    int p1 = (v1 + 7) & ~7;
    int s = p0 + p1;
    sc[tid] = s;
    __syncthreads();
    for (int st = 1; st < 256; st <<= 1) {
        int t = (tid >= st) ? sc[tid - st] : 0;
        __syncthreads();
        sc[tid] += t;
        __syncthreads();
    }
    int excl = sc[tid] - s;
    int c0 = obase + excl;
    int c1 = c0 + p0;
    cur[2 * tid] = c0;
    cur[2 * tid + 1] = c1;
    int n0 = node_base + 2 * tid;
    if (n0 < NN)     nd[r * NN + n0]     = make_int2(v0, c0);
    if (n0 + 1 < NN) nd[r * NN + n0 + 1] = make_int2(v1, c1);
    __syncthreads();
    for (int i = tid; i < count; i += 256) {
        uint p = pp[i];
        int pos = atomicAdd(&cur[p & 511], 1);
        srclist[pos] = (p >> 1) & ~255u;     // src*256 (pre-scaled byte offset)
    }
    __syncthreads();
    for (int i = v0; i < p0; ++i) srclist[c0 + i] = ZROW;
    for (int i = v1; i < p1; ++i) srclist[c1 + i] = ZROW;
}

// ---------------- gather-mean body: 3 relations interleaved, branch-free ----------------
template <int PHASE>
__device__ __forceinline__ void gather_body(
    int node, int tid,
    const ushort* __restrict__ f0, const ushort* __restrict__ f1,
    const ushort* __restrict__ f2, const int2* __restrict__ nd,
    const uint* __restrict__ srclist,
    ushort* __restrict__ ob, float* __restrict__ of) {
    int lane = tid & 63;
    int g = lane >> 4;
    uint c16 = (uint)(lane & 15) * 16;
    const char* fp0 = (const char*)f0;
    const char* fp1 = (const char*)f1;
    const char* fp2 = (const char*)f2;

    int2 q0 = nd[node];
    int2 q1 = nd[NN + node];
    int2 q2 = nd[2 * NN + node];
    int d0 = q0.x, d1 = q1.x, d2 = q2.x;
    int pd0 = (d0 + 7) & ~7, pd1 = (d1 + 7) & ~7, pd2 = (d2 + 7) & ~7;
    uint sid0 = srclist[q0.y + lane];
    uint sid1 = srclist[q1.y + lane];
    uint sid2 = srclist[q2.y + lane];

    f32x2 a0[4], a1[4], a2[4];
#pragma unroll
    for (int k = 0; k < 4; ++k) { a0[k] = 0.f; a1[k] = 0.f; a2[k] = 0.f; }

    uint zoff = ZROW + c16;
    int pmax = max(max(pd0, pd1), pd2);
    int pm64 = min(pmax, 64);
    for (int j0 = 0; j0 < pm64; j0 += 8) {
        uint oA = (j0 < pd0) ? (__shfl(sid0, j0 + g) + c16) : zoff;
        uint oB = (j0 < pd0) ? (__shfl(sid0, j0 + 4 + g) + c16) : zoff;
        uint oC = (j0 < pd1) ? (__shfl(sid1, j0 + g) + c16) : zoff;
        uint oD = (j0 < pd1) ? (__shfl(sid1, j0 + 4 + g) + c16) : zoff;
        uint oE = (j0 < pd2) ? (__shfl(sid2, j0 + g) + c16) : zoff;
        uint oF = (j0 < pd2) ? (__shfl(sid2, j0 + 4 + g) + c16) : zoff;
        uint4 vA = *(const uint4*)(fp0 + oA);
        uint4 vB = *(const uint4*)(fp0 + oB);
        uint4 vC = *(const uint4*)(fp1 + oC);
        uint4 vD = *(const uint4*)(fp1 + oD);
        uint4 vE = *(const uint4*)(fp2 + oE);
        uint4 vF = *(const uint4*)(fp2 + oF);
        acc16(a0, vA); acc16(a0, vB);
        acc16(a1, vC); acc16(a1, vD);
        acc16(a2, vE); acc16(a2, vF);
    }
    // rare tails (degree > 64)
    if (pmax > 64) {
        for (int i0 = 64; i0 < pd0; i0 += 64) {
            uint sl = srclist[q0.y + i0 + lane];
            int lim = min(pd0 - i0, 64);
            for (int j0 = 0; j0 < lim; j0 += 8) {
                uint u1 = __shfl(sl, j0 + g) + c16, u2 = __shfl(sl, j0 + 4 + g) + c16;
                acc16(a0, *(const uint4*)(fp0 + u1));
                acc16(a0, *(const uint4*)(fp0 + u2));
            }
        }
        for (int i0 = 64; i0 < pd1; i0 += 64) {
            uint sl = srclist[q1.y + i0 + lane];
            int lim = min(pd1 - i0, 64);
            for (int j0 = 0; j0 < lim; j0 += 8) {
                uint u1 = __shfl(sl, j0 + g) + c16, u2 = __shfl(sl, j0 + 4 + g) + c16;
                acc16(a1, *(const uint4*)(fp1 + u1));
                acc16(a1, *(const uint4*)(fp1 + u2));
            }
        }
        for (int i0 = 64; i0 < pd2; i0 += 64) {
            uint sl = srclist[q2.y + i0 + lane];
            int lim = min(pd2 - i0, 64);
            for (int j0 = 0; j0 < lim; j0 += 8) {
                uint u1 = __shfl(sl, j0 + g) + c16, u2 = __shfl(sl, j0 + 4 + g) + c16;
                acc16(a2, *(const uint4*)(fp2 + u1));
                acc16(a2, *(const uint4*)(fp2 + u2));
            }
        }
    }

    // reduce the 4 g-groups (lanes c, c+16, c+32, c+48)
#pragma unroll
    for (int k = 0; k < 4; ++k) {
        a0[k].x += __shfl_xor(a0[k].x, 16); a0[k].y += __shfl_xor(a0[k].y, 16);
        a0[k].x += __shfl_xor(a0[k].x, 32); a0[k].y += __shfl_xor(a0[k].y, 32);
        a1[k].x += __shfl_xor(a1[k].x, 16); a1[k].y += __shfl_xor(a1[k].y, 16);
        a1[k].x += __shfl_xor(a1[k].x, 32); a1[k].y += __shfl_xor(a1[k].y, 32);
        a2[k].x += __shfl_xor(a2[k].x, 16); a2[k].y += __shfl_xor(a2[k].y, 16);
        a2[k].x += __shfl_xor(a2[k].x, 32); a2[k].y += __shfl_xor(a2[k].y, 32);
    }
    float inv0 = 1.f / fmaxf((float)d0, 1.f);
    float inv1 = 1.f / fmaxf((float)d1, 1.f);
    float inv2 = 1.f / fmaxf((float)d2, 1.f);
    if (PHASE == 0) {
        if (g == 0) {
            size_t base = (size_t)node * 128 + (c16 >> 1);
            size_t rstride = (size_t)(NN + 1) * DIN;
            uint4 pk;
            pk.x = (uint)f2bf(a0[0].x * inv0) | ((uint)f2bf(a0[0].y * inv0) << 16);
            pk.y = (uint)f2bf(a0[1].x * inv0) | ((uint)f2bf(a0[1].y * inv0) << 16);
            pk.z = (uint)f2bf(a0[2].x * inv0) | ((uint)f2bf(a0[2].y * inv0) << 16);
            pk.w = (uint)f2bf(a0[3].x * inv0) | ((uint)f2bf(a0[3].y * inv0) << 16);
            *(uint4*)(ob + base) = pk;
            pk.x = (uint)f2bf(a1[0].x * inv1) | ((uint)f2bf(a1[0].y * inv1) << 16);
            pk.y = (uint)f2bf(a1[1].x * inv1) | ((uint)f2bf(a1[1].y * inv1) << 16);
            pk.z = (uint)f2bf(a1[2].x * inv1) | ((uint)f2bf(a1[2].y * inv1) << 16);
            pk.w = (uint)f2bf(a1[3].x * inv1) | ((uint)f2bf(a1[3].y * inv1) << 16);
            *(uint4*)(ob + rstride + base) = pk;
            pk.x = (uint)f2bf(a2[0].x * inv2) | ((uint)f2bf(a2[0].y * inv2) << 16);
            pk.y = (uint)f2bf(a2[1].x * inv2) | ((uint)f2bf(a2[1].y * inv2) << 16);
            pk.z = (uint)f2bf(a2[2].x * inv2) | ((uint)f2bf(a2[2].y * inv2) << 16);
            pk.w = (uint)f2bf(a2[3].x * inv2) | ((uint)f2bf(a2[3].y * inv2) << 16);
            *(uint4*)(ob + 2 * rstride + base) = pk;
        }
    } else {
        if (g == 0) {
            float* po = of + (size_t)node * 128 + (c16 >> 1);
            float4 a = *(float4*)po;
            float4 b = *(float4*)(po + 4);
            a.x += a0[0].x * inv0 + a1[0].x * inv1 + a2[0].x * inv2;
            a.y += a0[0].y * inv0 + a1[0].y * inv1 + a2[0].y * inv2;
            a.z += a0[1].x * inv0 + a1[1].x * inv1 + a2[1].x * inv2;
            a.w += a0[1].y * inv0 + a1[1].y * inv1 + a2[1].y * inv2;
            b.x += a0[2].x * inv0 + a1[2].x * inv1 + a2[2].x * inv2;
            b.y += a0[2].y * inv0 + a1[2].y * inv1 + a2[2].y * inv2;
            b.z += a0[3].x * inv0 + a1[3].x * inv1 + a2[3].x * inv2;
            b.w += a0[3].y * inv0 + a1[3].y * inv1 + a2[3].y * inv2;
            *(float4*)po = a;
            *(float4*)(po + 4) = b;
        }
    }
}

// ---------------- fused dispatch: layer-1 gather + layer-1 SELF GEMM ----------------
// Blocks [0, MM1S_BLKS): 128x128-tile GEMM Hb_self = xb @ Bt1[:, 0:128] (bf16, no bias/relu).
// Blocks [MM1S_BLKS, ...): gather phase-0 (agg_r = mean_r(x)).
// The gather is latency-bound (0% MFMA, ~44% VALU) -> the GEMM blocks ride its idle slots.
__global__ __launch_bounds__(256) void g1_fused(
    const ushort* __restrict__ xb, const int2* __restrict__ nd,
    const uint* __restrict__ srclist, ushort* __restrict__ aggb,
    const ushort* __restrict__ Bt1, ushort* __restrict__ Hb) {
    if (blockIdx.x >= MM1S_BLKS) {
        int node = (blockIdx.x - MM1S_BLKS) * 4 + (threadIdx.x >> 6);
        if (node < NN)
            gather_body<0>(node, threadIdx.x, xb, xb, xb, nd, srclist, aggb, nullptr);
        return;
    }
    // ---- self GEMM path: BM=128, BN=128, BK=32, K=128, 4 waves (2x2), 64x64/wave
    __shared__ __align__(16) ushort As[128 * 32];
    __shared__ __align__(16) ushort Bs[128 * 32];
    const int tid = threadIdx.x, lane = tid & 63, w = tid >> 6;
    const int wr = w >> 1, wc = w & 1;
    const int bm = (blockIdx.x % 391) * 128;
    const int bn = (blockIdx.x / 391) * 128;

    f32x4 acc[4][4];
#pragma unroll
    for (int m = 0; m < 4; ++m)
#pragma unroll
        for (int n = 0; n < 4; ++n) acc[m][n] = (f32x4){0.f, 0.f, 0.f, 0.f};

    const int arow = lane >> 2;       // row within 16-row chunk
    const int akq = (lane & 3) * 8;   // ushort offset within row

    for (int k0 = 0; k0 < 128; k0 += 32) {
#pragma unroll
        for (int i = 0; i < 2; ++i) {
            int c = w + i * 4;
            const ushort* srcA = xb + (size_t)(bm + c * 16 + arow) * 128 + k0 + akq;
            __builtin_amdgcn_global_load_lds((gptr_t)srcA, (lptr_t)(As + c * 512), 16, 0, 0);
            const ushort* srcB = Bt1 + (size_t)(bn + c * 16 + arow) * 512 + k0 + akq;
            __builtin_amdgcn_global_load_lds((gptr_t)srcB, (lptr_t)(Bs + c * 512), 16, 0, 0);
        }
        __syncthreads();
        const int r = lane & 15, g = lane >> 4;
        bf16x8 af[4], bg[4];
#pragma unroll
        for (int m = 0; m < 4; ++m)
            af[m] = *(const bf16x8*)&As[(wr * 64 + m * 16 + r) * 32 + g * 8];
#pragma unroll
        for (int n = 0; n < 4; ++n)
            bg[n] = *(const bf16x8*)&Bs[(wc * 64 + n * 16 + r) * 32 + g * 8];
#pragma unroll
        for (int m = 0; m < 4; ++m)
#pragma unroll
            for (int n = 0; n < 4; ++n)
                acc[m][n] = __builtin_amdgcn_mfma_f32_16x16x32_bf16(af[m], bg[n], acc[m][n], 0, 0, 0);
        __syncthreads();
    }
    const int r = lane & 15, g = lane >> 4;
#pragma unroll
    for (int m = 0; m < 4; ++m)
#pragma unroll
        for (int v = 0; v < 4; ++v) {
            int gm = bm + wr * 64 + m * 16 + g * 4 + v;
            if (gm >= NN) continue;
#pragma unroll
            for (int n = 0; n < 4; ++n) {
                int gn = bn + wc * 64 + n * 16 + r;
                Hb[(size_t)gm * 256 + gn] = f2bf(acc[m][n][v]);
            }
        }
}

// ---------------- layer-2 gather ----------------
__global__ __launch_bounds__(256) void gather_p1(
    const ushort* __restrict__ f0, const ushort* __restrict__ f1,
    const ushort* __restrict__ f2, const int2* __restrict__ nd,
    const uint* __restrict__ srclist, float* __restrict__ of) {
    int node = blockIdx.x * 4 + (threadIdx.x >> 6);
    if (node < NN)
        gather_body<1>(node, threadIdx.x, f0, f1, f2, nd, srclist, nullptr, of);
}

// ---------------- bf16 MFMA GEMM: 128x256 tile, BK=32, 512 threads (2x4 waves) ----------------
// LAYER 1 (neighbor-only): A = agg0..2 k-blocked (K=384), B = Bt1 cols k=128.. (stride 512),
//          epilogue: H = relu(acc + H_self + bias), grid (391,1).
// LAYER 2: A = H [M][256] (K=256), grid (391,2); buffer = (bn>>7)+(wc>>1):
//          0 -> out fp32 [M][128] (+bias), 1..3 -> Y_r bf16 [M][128].
template <int LAYER>
__global__ __launch_bounds__(512) void gemm_mfma(
    const ushort* __restrict__ A0, const ushort* __restrict__ A1,
    const ushort* __restrict__ A2, const ushort* __restrict__ Bt,
    const float* __restrict__ bias,
    ushort* __restrict__ HO, float* __restrict__ CO,
    ushort* __restrict__ Y1, ushort* __restrict__ Y2, ushort* __restrict__ Y3) {
    constexpr int KTOT = (LAYER == 1) ? 384 : 256;
    constexpr int ASTRIDE = (LAYER == 1) ? 128 : 256;
    constexpr int BSTRIDE = (LAYER == 1) ? 512 : 256;
    constexpr int BKOFF = (LAYER == 1) ? 128 : 0;
    __shared__ __align__(16) ushort As[128 * 32];   // 8 KB
    __shared__ __align__(16) ushort Bs[256 * 32];   // 16 KB

    const int tid = threadIdx.x, lane = tid & 63, w = tid >> 6;
    const int wr = w >> 2, wc = w & 3;
    const int bm = blockIdx.x * 128;
    const int bn = blockIdx.y * 256;

    f32x4 acc[4][4];
#pragma unroll
    for (int m = 0; m < 4; ++m)
#pragma unroll
        for (int n = 0; n < 4; ++n) acc[m][n] = (f32x4){0.f, 0.f, 0.f, 0.f};

    const int srow = tid >> 2;          // staging row 0..127
    const int schunk = (tid & 3) * 8;   // ushort offset within row

    for (int k0 = 0; k0 < KTOT; k0 += 32) {
        const ushort* Ab = A0;
        int koff = k0;
        if (LAYER == 1) {
            int b = k0 >> 7;
            Ab = (b == 0) ? A0 : (b == 1) ? A1 : A2;
            koff = k0 & 127;
        }
        {
            const ushort* srcA = Ab + (size_t)(bm + srow) * ASTRIDE + koff + schunk;
            __builtin_amdgcn_global_load_lds((gptr_t)srcA, (lptr_t)(As + w * 512), 16, 0, 0);
        }
#pragma unroll
        for (int i = 0; i < 2; ++i) {
            int row = i * 128 + srow;
            const ushort* srcB = Bt + (size_t)(bn + row) * BSTRIDE + BKOFF + k0 + schunk;
            __builtin_amdgcn_global_load_lds((gptr_t)srcB, (lptr_t)(Bs + i * 4096 + w * 512), 16, 0, 0);
        }
        __syncthreads();

        const int r = lane & 15, g = lane >> 4;
        bf16x8 af[4], bg[4];
#pragma unroll
        for (int m = 0; m < 4; ++m)
            af[m] = *(const bf16x8*)&As[(wr * 64 + m * 16 + r) * 32 + g * 8];
#pragma unroll
        for (int n = 0; n < 4; ++n)
            bg[n] = *(const bf16x8*)&Bs[(wc * 64 + n * 16 + r) * 32 + g * 8];
#pragma unroll
        for (int m = 0; m < 4; ++m)
#pragma unroll
            for (int n = 0; n < 4; ++n)
                acc[m][n] = __builtin_amdgcn_mfma_f32_16x16x32_bf16(af[m], bg[n], acc[m][n], 0, 0, 0);
        __syncthreads();
    }

    const int r = lane & 15, g = lane >> 4;
    if (LAYER == 1) {
#pragma unroll
        for (int m = 0; m < 4; ++m)
#pragma unroll
            for (int v = 0; v < 4; ++v) {
                int gm = bm + wr * 64 + m * 16 + g * 4 + v;
                if (gm >= NN) continue;
#pragma unroll
                for (int n = 0; n < 4; ++n) {
                    int gn = wc * 64 + n * 16 + r;
                    size_t idx = (size_t)gm * 256 + gn;
                    float hself = __uint_as_float(((uint)HO[idx]) << 16);
                    float f = acc[m][n][v] + hself + bias[gn];
                    HO[idx] = f2bf(fmaxf(f, 0.f));
                }
            }
    } else {
        int buf = (bn >> 7) + (wc >> 1);          // wave-uniform: 0..3
        ushort* Y = (buf == 1) ? Y1 : (buf == 2) ? Y2 : Y3;
#pragma unroll
        for (int m = 0; m < 4; ++m)
#pragma unroll
            for (int v = 0; v < 4; ++v) {
                int gm = bm + wr * 64 + m * 16 + g * 4 + v;
                if (gm >= NN) continue;
#pragma unroll
                for (int n = 0; n < 4; ++n) {
                    int col = (wc & 1) * 64 + n * 16 + r;
                    if (buf == 0)
                        CO[(size_t)gm * 128 + col] = acc[m][n][v] + bias[col];
                    else
                        Y[(size_t)gm * 128 + col] = f2bf(acc[m][n][v]);
                }
            }
    }
}

// ---------------- launch ----------------
extern "C" void kernel_launch(void* const* d_in, const int* in_sizes, int n_in,
                              void* d_out, int out_size, void* d_ws, size_t ws_size,
                              hipStream_t stream) {
    const float* x        = (const float*)d_in[0];
    const int*   src      = (const int*)d_in[1];
    const int*   dst      = (const int*)d_in[2];
    const float* w_self1  = (const float*)d_in[3];
    const float* w_neigh1 = (const float*)d_in[4];
    const float* b1       = (const float*)d_in[5];
    const float* w_self2  = (const float*)d_in[6];
    const float* w_neigh2 = (const float*)d_in[7];
    const float* b2       = (const float*)d_in[8];
    float* out = (float*)d_out;

    char* ws = (char*)d_ws;
    size_t off = 0;
    auto alloc = [&](size_t bytes) {
        char* p = ws + off;
        off += (bytes + 255) & ~(size_t)255;
        return p;
    };
    const size_t NROW = NN + 1;   // feature buffers carry a zero row at index NN
    int*    bcursor = (int*)alloc(NREL * NBUK * 4);
    int2*   nd      = (int2*)alloc((size_t)NREL * NN * 8);
    uint*   srclist = (uint*)alloc(((size_t)NREL * NBUK * CAP + 256) * 4);  // +guard
    float*  bsum1   = (float*)alloc(DHID * 4);
    float*  bsum2   = (float*)alloc(DOUT * 4);
    ushort* Bt1     = (ushort*)alloc((size_t)DHID * 512 * 2);
    ushort* Bt2     = (ushort*)alloc((size_t)512 * DHID * 2);
    ushort* xb      = (ushort*)alloc(NROW * DIN * 2);
    ushort* aggb    = (ushort*)alloc((size_t)NREL * NROW * DIN * 2);
    ushort* Hb      = (ushort*)alloc((size_t)NN * DHID * 2);
    (void)alloc(65536); // guard for GEMM tile over-reads past last M-block
    // pairs buffer aliases Hb: consumed by pass_b before the g1_fused GEMM writes Hb.
    uint* pairs = (uint*)Hb;   // 3*98*8192*4 = 9.6 MB < 25.6 MB
    ushort* agg0 = aggb;
    ushort* agg1 = aggb + NROW * DIN;
    ushort* agg2 = aggb + 2 * NROW * DIN;

    // ---- pass A (bucketing) + prep (xb/Bt1/Bt2/bias/zero-rows), one dispatch
    hipMemsetAsync(bcursor, 0, NREL * NBUK * 4, stream);
    pass_a_prep<<<PA_BLKS + F2B_BLKS + 1024 + 1, 256, 0, stream>>>(
        src, dst, bcursor, pairs,
        x, xb, w_self1, w_neigh1, Bt1, w_self2, w_neigh2, Bt2,
        b1, bsum1, b2, bsum2, agg0, agg1, agg2);
    // ---- pass B: padded per-bucket CSR
    pass_b<<<NREL * NBUK, 256, 0, stream>>>(pairs, bcursor, srclist, nd);

    int ggrid = (NN + 3) / 4;   // 12500

    // ---- fused: layer-1 gather (agg_r) + layer-1 SELF GEMM (Hb_self = xb@Bt1[:,0:128])
    g1_fused<<<MM1S_BLKS + ggrid, 256, 0, stream>>>(xb, nd, srclist, aggb, Bt1, Hb);
    // ---- layer-1 neighbor GEMM: H = relu(H_self + [agg0|agg1|agg2]@Bt1[:,128:512]^T + bsum1)
    {
        dim3 grid((NN + 127) / 128, 1);
        gemm_mfma<1><<<grid, 512, 0, stream>>>(
            agg0, agg1, agg2, Bt1, bsum1, Hb, nullptr, nullptr, nullptr, nullptr);
    }
    // ---- layer 2 fused GEMM: [out | y0 | y1 | y2] = H @ Bt2^T (+bias on out)
    {
        dim3 grid((NN + 127) / 128, 2);
        gemm_mfma<2><<<grid, 512, 0, stream>>>(
            Hb, nullptr, nullptr, Bt2, bsum2,
            nullptr, out, agg0, agg1, agg2);
    }
    // ---- layer 2: out += sum_r mean_r(y_r), one RMW of out
    gather_p1<<<ggrid, 256, 0, stream>>>(agg0, agg1, agg2, nd, srclist, out);
}

// Round 9
// 224.806 us; speedup vs baseline: 1.2122x; 1.2122x over previous
//
#include <hip/hip_runtime.h>

#define NN 50000
#define NREL 3
#define NE 500000
#define DIN 128
#define DHID 256
#define DOUT 128

#define NBUK 98          // ceil(50000/512) dst-buckets of 512 nodes
#define CAP 8192         // padded-slot capacity per bucket (E~6900, sd~100)
#define EPB 4096         // edges per pass-A block
#define NCHK ((NE + EPB - 1) / EPB)   // 123
#define PA_BLKS (NREL * NCHK)         // 369
#define F2B_BLKS 6250                 // NN*DIN/4/256
#define ZROW ((uint)NN << 8)          // scaled dummy -> zero row (byte offset)

typedef unsigned int uint;
typedef unsigned short ushort;
typedef __attribute__((ext_vector_type(8))) short bf16x8;
typedef __attribute__((ext_vector_type(4))) float f32x4;
typedef __attribute__((ext_vector_type(2))) float f32x2;

using gptr_t = const __attribute__((address_space(1))) unsigned int*;
using lptr_t = __attribute__((address_space(3))) unsigned int*;

__device__ __forceinline__ ushort f2bf(float f) {
    uint u = __float_as_uint(f);
    uint r = (u + 0x7fffu + ((u >> 16) & 1u)) >> 16;
    return (ushort)r;
}
__device__ __forceinline__ void acc2(f32x2& a, uint u) {
    f32x2 t;
    t.x = __uint_as_float(u << 16);
    t.y = __uint_as_float(u & 0xffff0000u);
    a += t;   // v_pk_add_f32
}
__device__ __forceinline__ void acc16(f32x2* a, uint4 v) {
    acc2(a[0], v.x); acc2(a[1], v.y); acc2(a[2], v.z); acc2(a[3], v.w);
}

// ---------------- pass A (bucket edges) + prep (fused grid) ----------------
__global__ __launch_bounds__(256) void pass_a_prep(
    const int* __restrict__ src, const int* __restrict__ dst,
    int* __restrict__ bcursor, uint* __restrict__ pairs,
    const float* __restrict__ x, ushort* __restrict__ xb,
    const float* __restrict__ ws1, const float* __restrict__ wn1, ushort* __restrict__ Bt1,
    const float* __restrict__ ws2, const float* __restrict__ wn2, ushort* __restrict__ Bt2,
    const float* __restrict__ b1, float* __restrict__ bsum1,
    const float* __restrict__ b2, float* __restrict__ bsum2,
    ushort* __restrict__ agg0, ushort* __restrict__ agg1, ushort* __restrict__ agg2) {
    int blk = blockIdx.x, tid = threadIdx.x;
    if (blk < PA_BLKS) {
        int r = blk / NCHK;
        int chunk = blk % NCHK;
        int e0 = chunk * EPB;
        int nedge = min(EPB, NE - e0);
        const int* S = src + (size_t)r * NE + e0;
        const int* D = dst + (size_t)r * NE + e0;
        __shared__ int cnt[NBUK], base[NBUK], cur[NBUK];
        if (tid < NBUK) { cnt[tid] = 0; cur[tid] = 0; }
        __syncthreads();
        uint pk[16];
        int bk[16];
        bool val[16];
#pragma unroll
        for (int j = 0; j < 16; ++j) {
            int e = j * 256 + tid;
            val[j] = e < nedge;
            int d = val[j] ? D[e] : 0;
            int s = val[j] ? S[e] : 0;
            bk[j] = d >> 9;
            pk[j] = ((uint)s << 9) | (uint)(d & 511);
            if (val[j]) atomicAdd(&cnt[bk[j]], 1);
        }
        __syncthreads();
        if (tid < NBUK) base[tid] = atomicAdd(&bcursor[r * NBUK + tid], cnt[tid]);
        __syncthreads();
#pragma unroll
        for (int j = 0; j < 16; ++j) {
            if (val[j]) {
                int slot = base[bk[j]] + atomicAdd(&cur[bk[j]], 1);
                if (slot < CAP) pairs[(size_t)(r * NBUK + bk[j]) * CAP + slot] = pk[j];
            }
        }
        return;
    }
    blk -= PA_BLKS;
    if (blk < F2B_BLKS) {
        int t = blk * 256 + tid;   // < NN*DIN/4, exact
        float4 v = *(const float4*)(x + (size_t)t * 4);
        uint2 p;
        p.x = (uint)f2bf(v.x) | ((uint)f2bf(v.y) << 16);
        p.y = (uint)f2bf(v.z) | ((uint)f2bf(v.w) << 16);
        *(uint2*)(xb + (size_t)t * 4) = p;
    } else if (blk < F2B_BLKS + 512) {
        int t = (blk - F2B_BLKS) * 256 + tid;  // < 256*512
        int n = t >> 9, k = t & 511;
        int b = k >> 7, kk = k & 127;
        float v;
        if (b == 0)
            v = ws1[kk * 256 + n] + ws1[128 * 256 + kk * 256 + n] + ws1[2 * 128 * 256 + kk * 256 + n];
        else
            v = wn1[(size_t)(b - 1) * 128 * 256 + kk * 256 + n];
        Bt1[t] = f2bf(v);
    } else if (blk < F2B_BLKS + 1024) {
        int t = (blk - F2B_BLKS - 512) * 256 + tid;  // < 512*256
        int n = t >> 8, k = t & 255;
        int c = n >> 7, j = n & 127;
        float v;
        if (c == 0)
            v = ws2[k * 128 + j] + ws2[256 * 128 + k * 128 + j] + ws2[2 * 256 * 128 + k * 128 + j];
        else
            v = wn2[(size_t)(c - 1) * 256 * 128 + k * 128 + j];
        Bt2[t] = f2bf(v);
    } else {
        // bias sums + zero rows (row NN of xb/agg0/agg1/agg2)
        if (tid < DHID) bsum1[tid] = b1[tid] + b1[DHID + tid] + b1[2 * DHID + tid];
        if (tid < DOUT) bsum2[tid] = b2[tid] + b2[DOUT + tid] + b2[2 * DOUT + tid];
        if (tid >= 192 && tid < 256) {
            int b = (tid - 192) >> 4, i = tid & 15;
            ushort* row = (b == 0) ? xb : (b == 1) ? agg0 : (b == 2) ? agg1 : agg2;
            uint4 z = {0u, 0u, 0u, 0u};
            *(uint4*)(row + (size_t)NN * 128 + i * 8) = z;
        }
    }
}

// ---------------- pass B: per-bucket CSR with 8-padded node slots ----------------
__global__ __launch_bounds__(256) void pass_b(const uint* __restrict__ pairs,
                                              const int* __restrict__ bcnt,
                                              uint* __restrict__ srclist,
                                              int2* __restrict__ nd) {
    int blk = blockIdx.x;
    int b = blk % NBUK;
    int r = blk / NBUK;
    int node_base = b * 512;
    int count = min(bcnt[blk], CAP);
    int obase = blk * CAP;
    const uint* pp = pairs + (size_t)blk * CAP;
    __shared__ int hist[512];
    __shared__ int cur[512];
    __shared__ int sc[256];
    int tid = threadIdx.x;
    hist[tid] = 0;
    hist[tid + 256] = 0;
    __syncthreads();
    for (int i = tid; i < count; i += 256) atomicAdd(&hist[pp[i] & 511], 1);
    __syncthreads();
    int v0 = hist[2 * tid], v1 = hist[2 * tid + 1];
    int p0 = (v0 + 7) & ~7;                 // padded slot sizes
    int p1 = (v1 + 7) & ~7;
    int s = p0 + p1;
    sc[tid] = s;
    __syncthreads();
    for (int st = 1; st < 256; st <<= 1) {
        int t = (tid >= st) ? sc[tid - st] : 0;
        __syncthreads();
        sc[tid] += t;
        __syncthreads();
    }
    int excl = sc[tid] - s;
    int c0 = obase + excl;
    int c1 = c0 + p0;
    cur[2 * tid] = c0;
    cur[2 * tid + 1] = c1;
    int n0 = node_base + 2 * tid;
    if (n0 < NN)     nd[r * NN + n0]     = make_int2(v0, c0);
    if (n0 + 1 < NN) nd[r * NN + n0 + 1] = make_int2(v1, c1);
    __syncthreads();
    for (int i = tid; i < count; i += 256) {
        uint p = pp[i];
        int pos = atomicAdd(&cur[p & 511], 1);
        srclist[pos] = (p >> 1) & ~255u;     // src*256 (pre-scaled byte offset)
    }
    __syncthreads();
    for (int i = v0; i < p0; ++i) srclist[c0 + i] = ZROW;
    for (int i = v1; i < p1; ++i) srclist[c1 + i] = ZROW;
}

// ---------------- gather-mean body: 3 relations interleaved, branch-free ----------------
template <int PHASE>
__device__ __forceinline__ void gather_body(
    int node, int tid,
    const ushort* __restrict__ f0, const ushort* __restrict__ f1,
    const ushort* __restrict__ f2, const int2* __restrict__ nd,
    const uint* __restrict__ srclist,
    ushort* __restrict__ ob, float* __restrict__ of) {
    int lane = tid & 63;
    int g = lane >> 4;
    uint c16 = (uint)(lane & 15) * 16;
    const char* fp0 = (const char*)f0;
    const char* fp1 = (const char*)f1;
    const char* fp2 = (const char*)f2;

    int2 q0 = nd[node];
    int2 q1 = nd[NN + node];
    int2 q2 = nd[2 * NN + node];
    int d0 = q0.x, d1 = q1.x, d2 = q2.x;
    int pd0 = (d0 + 7) & ~7, pd1 = (d1 + 7) & ~7, pd2 = (d2 + 7) & ~7;
    uint sid0 = srclist[q0.y + lane];
    uint sid1 = srclist[q1.y + lane];
    uint sid2 = srclist[q2.y + lane];

    f32x2 a0[4], a1[4], a2[4];
#pragma unroll
    for (int k = 0; k < 4; ++k) { a0[k] = 0.f; a1[k] = 0.f; a2[k] = 0.f; }

    uint zoff = ZROW + c16;
    int pmax = max(max(pd0, pd1), pd2);
    int pm64 = min(pmax, 64);
    for (int j0 = 0; j0 < pm64; j0 += 8) {
        uint oA = (j0 < pd0) ? (__shfl(sid0, j0 + g) + c16) : zoff;
        uint oB = (j0 < pd0) ? (__shfl(sid0, j0 + 4 + g) + c16) : zoff;
        uint oC = (j0 < pd1) ? (__shfl(sid1, j0 + g) + c16) : zoff;
        uint oD = (j0 < pd1) ? (__shfl(sid1, j0 + 4 + g) + c16) : zoff;
        uint oE = (j0 < pd2) ? (__shfl(sid2, j0 + g) + c16) : zoff;
        uint oF = (j0 < pd2) ? (__shfl(sid2, j0 + 4 + g) + c16) : zoff;
        uint4 vA = *(const uint4*)(fp0 + oA);
        uint4 vB = *(const uint4*)(fp0 + oB);
        uint4 vC = *(const uint4*)(fp1 + oC);
        uint4 vD = *(const uint4*)(fp1 + oD);
        uint4 vE = *(const uint4*)(fp2 + oE);
        uint4 vF = *(const uint4*)(fp2 + oF);
        acc16(a0, vA); acc16(a0, vB);
        acc16(a1, vC); acc16(a1, vD);
        acc16(a2, vE); acc16(a2, vF);
    }
    // rare tails (degree > 64)
    if (pmax > 64) {
        for (int i0 = 64; i0 < pd0; i0 += 64) {
            uint sl = srclist[q0.y + i0 + lane];
            int lim = min(pd0 - i0, 64);
            for (int j0 = 0; j0 < lim; j0 += 8) {
                uint u1 = __shfl(sl, j0 + g) + c16, u2 = __shfl(sl, j0 + 4 + g) + c16;
                acc16(a0, *(const uint4*)(fp0 + u1));
                acc16(a0, *(const uint4*)(fp0 + u2));
            }
        }
        for (int i0 = 64; i0 < pd1; i0 += 64) {
            uint sl = srclist[q1.y + i0 + lane];
            int lim = min(pd1 - i0, 64);
            for (int j0 = 0; j0 < lim; j0 += 8) {
                uint u1 = __shfl(sl, j0 + g) + c16, u2 = __shfl(sl, j0 + 4 + g) + c16;
                acc16(a1, *(const uint4*)(fp1 + u1));
                acc16(a1, *(const uint4*)(fp1 + u2));
            }
        }
        for (int i0 = 64; i0 < pd2; i0 += 64) {
            uint sl = srclist[q2.y + i0 + lane];
            int lim = min(pd2 - i0, 64);
            for (int j0 = 0; j0 < lim; j0 += 8) {
                uint u1 = __shfl(sl, j0 + g) + c16, u2 = __shfl(sl, j0 + 4 + g) + c16;
                acc16(a2, *(const uint4*)(fp2 + u1));
                acc16(a2, *(const uint4*)(fp2 + u2));
            }
        }
    }

    // reduce the 4 g-groups (lanes c, c+16, c+32, c+48)
#pragma unroll
    for (int k = 0; k < 4; ++k) {
        a0[k].x += __shfl_xor(a0[k].x, 16); a0[k].y += __shfl_xor(a0[k].y, 16);
        a0[k].x += __shfl_xor(a0[k].x, 32); a0[k].y += __shfl_xor(a0[k].y, 32);
        a1[k].x += __shfl_xor(a1[k].x, 16); a1[k].y += __shfl_xor(a1[k].y, 16);
        a1[k].x += __shfl_xor(a1[k].x, 32); a1[k].y += __shfl_xor(a1[k].y, 32);
        a2[k].x += __shfl_xor(a2[k].x, 16); a2[k].y += __shfl_xor(a2[k].y, 16);
        a2[k].x += __shfl_xor(a2[k].x, 32); a2[k].y += __shfl_xor(a2[k].y, 32);
    }
    float inv0 = 1.f / fmaxf((float)d0, 1.f);
    float inv1 = 1.f / fmaxf((float)d1, 1.f);
    float inv2 = 1.f / fmaxf((float)d2, 1.f);
    if (PHASE == 0) {
        if (g == 0) {
            size_t base = (size_t)node * 128 + (c16 >> 1);
            size_t rstride = (size_t)(NN + 1) * DIN;
            uint4 pk;
            pk.x = (uint)f2bf(a0[0].x * inv0) | ((uint)f2bf(a0[0].y * inv0) << 16);
            pk.y = (uint)f2bf(a0[1].x * inv0) | ((uint)f2bf(a0[1].y * inv0) << 16);
            pk.z = (uint)f2bf(a0[2].x * inv0) | ((uint)f2bf(a0[2].y * inv0) << 16);
            pk.w = (uint)f2bf(a0[3].x * inv0) | ((uint)f2bf(a0[3].y * inv0) << 16);
            *(uint4*)(ob + base) = pk;
            pk.x = (uint)f2bf(a1[0].x * inv1) | ((uint)f2bf(a1[0].y * inv1) << 16);
            pk.y = (uint)f2bf(a1[1].x * inv1) | ((uint)f2bf(a1[1].y * inv1) << 16);
            pk.z = (uint)f2bf(a1[2].x * inv1) | ((uint)f2bf(a1[2].y * inv1) << 16);
            pk.w = (uint)f2bf(a1[3].x * inv1) | ((uint)f2bf(a1[3].y * inv1) << 16);
            *(uint4*)(ob + rstride + base) = pk;
            pk.x = (uint)f2bf(a2[0].x * inv2) | ((uint)f2bf(a2[0].y * inv2) << 16);
            pk.y = (uint)f2bf(a2[1].x * inv2) | ((uint)f2bf(a2[1].y * inv2) << 16);
            pk.z = (uint)f2bf(a2[2].x * inv2) | ((uint)f2bf(a2[2].y * inv2) << 16);
            pk.w = (uint)f2bf(a2[3].x * inv2) | ((uint)f2bf(a2[3].y * inv2) << 16);
            *(uint4*)(ob + 2 * rstride + base) = pk;
        }
    } else {
        if (g == 0) {
            float* po = of + (size_t)node * 128 + (c16 >> 1);
            float4 a = *(float4*)po;
            float4 b = *(float4*)(po + 4);
            a.x += a0[0].x * inv0 + a1[0].x * inv1 + a2[0].x * inv2;
            a.y += a0[0].y * inv0 + a1[0].y * inv1 + a2[0].y * inv2;
            a.z += a0[1].x * inv0 + a1[1].x * inv1 + a2[1].x * inv2;
            a.w += a0[1].y * inv0 + a1[1].y * inv1 + a2[1].y * inv2;
            b.x += a0[2].x * inv0 + a1[2].x * inv1 + a2[2].x * inv2;
            b.y += a0[2].y * inv0 + a1[2].y * inv1 + a2[2].y * inv2;
            b.z += a0[3].x * inv0 + a1[3].x * inv1 + a2[3].x * inv2;
            b.w += a0[3].y * inv0 + a1[3].y * inv1 + a2[3].y * inv2;
            *(float4*)po = a;
            *(float4*)(po + 4) = b;
        }
    }
}

__global__ __launch_bounds__(256) void gather_p0(
    const ushort* __restrict__ xb, const int2* __restrict__ nd,
    const uint* __restrict__ srclist, ushort* __restrict__ aggb) {
    int node = blockIdx.x * 4 + (threadIdx.x >> 6);
    if (node < NN)
        gather_body<0>(node, threadIdx.x, xb, xb, xb, nd, srclist, aggb, nullptr);
}

__global__ __launch_bounds__(256) void gather_p1(
    const ushort* __restrict__ f0, const ushort* __restrict__ f1,
    const ushort* __restrict__ f2, const int2* __restrict__ nd,
    const uint* __restrict__ srclist, float* __restrict__ of) {
    int node = blockIdx.x * 4 + (threadIdx.x >> 6);
    if (node < NN)
        gather_body<1>(node, threadIdx.x, f0, f1, f2, nd, srclist, nullptr, of);
}

// ---------------- bf16 MFMA GEMM: 128x256 tile, BK=32, 512 threads (2x4 waves) ----------------
// Double-buffered LDS + counted vmcnt 2-phase pipeline (stage t+1 while computing t;
// drain only the current tile's 3 loads, raw s_barrier instead of full __syncthreads drain).
// LAYER 1: A = 4 k-blocked buffers [M][128] (K=512), C = H bf16 [M][256], bias+relu. grid (391,1)
// LAYER 2: A = H [M][256] (K=256), grid (391,2); buffer = (bn>>7)+(wc>>1):
//          0 -> out fp32 [M][128] (+bias), 1..3 -> Y_r bf16 [M][128].
template <int LAYER>
__global__ __launch_bounds__(512) void gemm_mfma(
    const ushort* __restrict__ A0, const ushort* __restrict__ A1,
    const ushort* __restrict__ A2, const ushort* __restrict__ A3,
    const ushort* __restrict__ Bt, const float* __restrict__ bias,
    ushort* __restrict__ HO, float* __restrict__ CO,
    ushort* __restrict__ Y1, ushort* __restrict__ Y2, ushort* __restrict__ Y3) {
    constexpr int KTOT = (LAYER == 1) ? 512 : 256;
    constexpr int ASTRIDE = (LAYER == 1) ? 128 : 256;
    constexpr int NT = KTOT / 32;
    __shared__ __align__(16) ushort As[2][128 * 32];   // 2 x 8 KB
    __shared__ __align__(16) ushort Bs[2][256 * 32];   // 2 x 16 KB

    const int tid = threadIdx.x, lane = tid & 63, w = tid >> 6;
    const int wr = w >> 2, wc = w & 3;
    const int bm = blockIdx.x * 128;
    const int bn = blockIdx.y * 256;
    const int srow = tid >> 2;          // staging row 0..127
    const int schunk = (tid & 3) * 8;   // ushort offset within row

    f32x4 acc[4][4];
#pragma unroll
    for (int m = 0; m < 4; ++m)
#pragma unroll
        for (int n = 0; n < 4; ++n) acc[m][n] = (f32x4){0.f, 0.f, 0.f, 0.f};

    auto stage = [&](int t, int buf) {
        int k0 = t * 32;
        const ushort* Ab = A0;
        int koff = k0;
        if (LAYER == 1) {
            int b = k0 >> 7;
            Ab = (b == 0) ? A0 : (b == 1) ? A1 : (b == 2) ? A2 : A3;
            koff = k0 & 127;
        }
        const ushort* srcA = Ab + (size_t)(bm + srow) * ASTRIDE + koff + schunk;
        __builtin_amdgcn_global_load_lds((gptr_t)srcA, (lptr_t)(&As[buf][w * 512]), 16, 0, 0);
#pragma unroll
        for (int i = 0; i < 2; ++i) {
            const ushort* srcB = Bt + (size_t)(bn + i * 128 + srow) * KTOT + k0 + schunk;
            __builtin_amdgcn_global_load_lds((gptr_t)srcB, (lptr_t)(&Bs[buf][i * 4096 + w * 512]), 16, 0, 0);
        }
    };

    stage(0, 0);
    const int r = lane & 15, g = lane >> 4;
    for (int t = 0; t < NT; ++t) {
        int cur = t & 1;
        if (t + 1 < NT) {
            stage(t + 1, cur ^ 1);
            asm volatile("s_waitcnt vmcnt(3)" ::: "memory");  // cur's 3 loads done; next's in flight
        } else {
            asm volatile("s_waitcnt vmcnt(0)" ::: "memory");
        }
        __builtin_amdgcn_s_barrier();
        asm volatile("" ::: "memory");
        bf16x8 af[4], bg[4];
#pragma unroll
        for (int m = 0; m < 4; ++m)
            af[m] = *(const bf16x8*)&As[cur][(wr * 64 + m * 16 + r) * 32 + g * 8];
#pragma unroll
        for (int n = 0; n < 4; ++n)
            bg[n] = *(const bf16x8*)&Bs[cur][(wc * 64 + n * 16 + r) * 32 + g * 8];
#pragma unroll
        for (int m = 0; m < 4; ++m)
#pragma unroll
            for (int n = 0; n < 4; ++n)
                acc[m][n] = __builtin_amdgcn_mfma_f32_16x16x32_bf16(af[m], bg[n], acc[m][n], 0, 0, 0);
        asm volatile("" ::: "memory");
        __builtin_amdgcn_s_barrier();
    }

    if (LAYER == 1) {
#pragma unroll
        for (int m = 0; m < 4; ++m)
#pragma unroll
            for (int v = 0; v < 4; ++v) {
                int gm = bm + wr * 64 + m * 16 + g * 4 + v;
                if (gm >= NN) continue;
#pragma unroll
                for (int n = 0; n < 4; ++n) {
                    int gn = wc * 64 + n * 16 + r;
                    float f = acc[m][n][v] + bias[gn];
                    f = fmaxf(f, 0.f);
                    HO[(size_t)gm * 256 + gn] = f2bf(f);
                }
            }
    } else {
        int buf = (bn >> 7) + (wc >> 1);          // wave-uniform: 0..3
        ushort* Y = (buf == 1) ? Y1 : (buf == 2) ? Y2 : Y3;
#pragma unroll
        for (int m = 0; m < 4; ++m)
#pragma unroll
            for (int v = 0; v < 4; ++v) {
                int gm = bm + wr * 64 + m * 16 + g * 4 + v;
                if (gm >= NN) continue;
#pragma unroll
                for (int n = 0; n < 4; ++n) {
                    int col = (wc & 1) * 64 + n * 16 + r;
                    if (buf == 0)
                        CO[(size_t)gm * 128 + col] = acc[m][n][v] + bias[col];
                    else
                        Y[(size_t)gm * 128 + col] = f2bf(acc[m][n][v]);
                }
            }
    }
}

// ---------------- launch ----------------
extern "C" void kernel_launch(void* const* d_in, const int* in_sizes, int n_in,
                              void* d_out, int out_size, void* d_ws, size_t ws_size,
                              hipStream_t stream) {
    const float* x        = (const float*)d_in[0];
    const int*   src      = (const int*)d_in[1];
    const int*   dst      = (const int*)d_in[2];
    const float* w_self1  = (const float*)d_in[3];
    const float* w_neigh1 = (const float*)d_in[4];
    const float* b1       = (const float*)d_in[5];
    const float* w_self2  = (const float*)d_in[6];
    const float* w_neigh2 = (const float*)d_in[7];
    const float* b2       = (const float*)d_in[8];
    float* out = (float*)d_out;

    char* ws = (char*)d_ws;
    size_t off = 0;
    auto alloc = [&](size_t bytes) {
        char* p = ws + off;
        off += (bytes + 255) & ~(size_t)255;
        return p;
    };
    const size_t NROW = NN + 1;   // feature buffers carry a zero row at index NN
    int*    bcursor = (int*)alloc(NREL * NBUK * 4);
    int2*   nd      = (int2*)alloc((size_t)NREL * NN * 8);
    uint*   srclist = (uint*)alloc(((size_t)NREL * NBUK * CAP + 256) * 4);  // +guard
    float*  bsum1   = (float*)alloc(DHID * 4);
    float*  bsum2   = (float*)alloc(DOUT * 4);
    ushort* Bt1     = (ushort*)alloc((size_t)DHID * 512 * 2);
    ushort* Bt2     = (ushort*)alloc((size_t)512 * DHID * 2);
    ushort* xb      = (ushort*)alloc(NROW * DIN * 2);
    ushort* aggb    = (ushort*)alloc((size_t)NREL * NROW * DIN * 2);
    ushort* Hb      = (ushort*)alloc((size_t)NN * DHID * 2);
    (void)alloc(65536); // guard for GEMM tile over-reads past last M-block
    // pairs buffer aliases Hb: consumed by pass_b before the layer-1 GEMM writes Hb.
    uint* pairs = (uint*)Hb;   // 3*98*8192*4 = 9.6 MB < 25.6 MB
    ushort* agg0 = aggb;
    ushort* agg1 = aggb + NROW * DIN;
    ushort* agg2 = aggb + 2 * NROW * DIN;

    // ---- pass A (bucketing) + prep (xb/Bt1/Bt2/bias/zero-rows), one dispatch
    hipMemsetAsync(bcursor, 0, NREL * NBUK * 4, stream);
    pass_a_prep<<<PA_BLKS + F2B_BLKS + 1024 + 1, 256, 0, stream>>>(
        src, dst, bcursor, pairs,
        x, xb, w_self1, w_neigh1, Bt1, w_self2, w_neigh2, Bt2,
        b1, bsum1, b2, bsum2, agg0, agg1, agg2);
    // ---- pass B: padded per-bucket CSR
    pass_b<<<NREL * NBUK, 256, 0, stream>>>(pairs, bcursor, srclist, nd);

    int ggrid = (NN + 3) / 4;   // 12500

    // ---- layer 1: agg_r = mean_r(x), all 3 relations interleaved in one kernel
    gather_p0<<<ggrid, 256, 0, stream>>>(xb, nd, srclist, aggb);
    // ---- layer 1 fused GEMM: H = relu([x|agg0|agg1|agg2] @ Bt1^T + bsum1)
    {
        dim3 grid((NN + 127) / 128, 1);
        gemm_mfma<1><<<grid, 512, 0, stream>>>(
            xb, agg0, agg1, agg2, Bt1, bsum1, Hb, nullptr, nullptr, nullptr, nullptr);
    }
    // ---- layer 2 fused GEMM: [out | y0 | y1 | y2] = H @ Bt2^T (+bias on out)
    {
        dim3 grid((NN + 127) / 128, 2);
        gemm_mfma<2><<<grid, 512, 0, stream>>>(
            Hb, nullptr, nullptr, nullptr, Bt2, bsum2,
            nullptr, out, agg0, agg1, agg2);
    }
    // ---- layer 2: out += sum_r mean_r(y_r), one RMW of out
    gather_p1<<<ggrid, 256, 0, stream>>>(agg0, agg1, agg2, nd, srclist, out);
}